// Round 13
// baseline (349.455 us; speedup 1.0000x reference)
//
#include <hip/hip_runtime.h>
#include <hip/hip_bf16.h>

typedef __hip_bfloat16 bf16;
typedef unsigned short u16;
typedef unsigned int u32;
typedef __attribute__((ext_vector_type(8))) short short8;
typedef __attribute__((ext_vector_type(4))) short bh4;
typedef __attribute__((ext_vector_type(4))) float floatx4;

constexpr int N_ = 2, H_ = 96, W_ = 96, HW_ = H_ * W_;
constexpr int CIN_ = 256, CH_ = 64, C2_ = 128;

__device__ __forceinline__ float sigm(float v) { return 1.0f / (1.0f + __expf(-v)); }
__device__ __forceinline__ short f2b(float v) { bf16 h = __float2bfloat16(v); return *reinterpret_cast<short*>(&h); }
__device__ __forceinline__ float b2f(short s) {
    union { u32 i; float f; } v; v.i = ((u32)(u16)s) << 16; return v.f;
}

// ---------- bf16 weight regions inside d_ws ----------
// conv A[m][k = tap*IC + ic];  dcn A[m][k = tap*128 + c]  (both tap-major)
constexpr int A_IN_OFF = 0,                         A_IN_SZ  = 64 * 2304;
constexpr int A_OUT_OFF = A_IN_OFF + A_IN_SZ,       A_OUT_SZ = 256 * 576;
constexpr int A_OFF_OFF = A_OUT_OFF + A_OUT_SZ,     A_OFF_SZ = 64 * 1152;   // 27 padded to 64
constexpr int A_DCN_OFF = A_OFF_OFF + 4 * A_OFF_SZ, A_DCN_SZ = 64 * 1152;
constexpr int A_TOT = A_DCN_OFF + 4 * A_DCN_SZ;     // 884736 shorts = 1.77 MB

__global__ __launch_bounds__(256) void cvt_weights(
        const float* __restrict__ w_in, const float* __restrict__ w_out,
        const float* __restrict__ ow0, const float* __restrict__ ow1,
        const float* __restrict__ ow2, const float* __restrict__ ow3,
        const float* __restrict__ w0, const float* __restrict__ w1,
        const float* __restrict__ w2, const float* __restrict__ w3,
        u16* __restrict__ dst) {
    int id = blockIdx.x * 256 + threadIdx.x;
    if (id >= A_TOT) return;
    float v;
    if (id < A_OUT_OFF) {
        int l = id; int m = l / 2304, k = l % 2304; int tap = k >> 8, ic = k & 255;
        v = w_in[m * 2304 + ic * 9 + tap];
    } else if (id < A_OFF_OFF) {
        int l = id - A_OUT_OFF; int m = l / 576, k = l % 576; int tap = k / 64, ic = k & 63;
        v = w_out[m * 576 + ic * 9 + tap];
    } else if (id < A_DCN_OFF) {
        int l = id - A_OFF_OFF; int i = l / A_OFF_SZ, l2 = l % A_OFF_SZ;
        int m = l2 / 1152, k = l2 % 1152; int tap = k >> 7, ic = k & 127;
        const float* s = (i == 0) ? ow0 : (i == 1) ? ow1 : (i == 2) ? ow2 : ow3;
        v = (m < 27) ? s[m * 1152 + ic * 9 + tap] : 0.f;
    } else {
        int l = id - A_DCN_OFF; int i = l / A_DCN_SZ, l2 = l % A_DCN_SZ;
        int m = l2 / 1152, k = l2 % 1152; int tap = k >> 7, c = k & 127;
        const float* s = (i == 0) ? w0 : (i == 1) ? w1 : (i == 2) ? w2 : w3;
        v = s[m * 1152 + c * 9 + tap];
    }
    short sb = f2b(v);
    dst[id] = *reinterpret_cast<u16*>(&sb);
}

// ---------- NCHW f32 -> NHWC bf16 ----------
__global__ __launch_bounds__(256) void to_nhwc(const float* __restrict__ src, u16* __restrict__ dst, int C) {
    int id = blockIdx.x * 256 + threadIdx.x;
    int c8n = C >> 3;
    if (id >= N_ * HW_ * c8n) return;
    int c8 = id % c8n;
    int pix = id / c8n;
    int n = pix / HW_, p = pix % HW_;
    const float* s = src + ((size_t)n * C + c8 * 8) * HW_ + p;
    short8 vv;
#pragma unroll
    for (int j = 0; j < 8; ++j) vv[j] = f2b(s[(size_t)j * HW_]);
    *reinterpret_cast<short8*>(dst + (size_t)pix * C + c8 * 8) = vv;
}

// ---------- dual concat: txh_a = concat(tpl, xh), txh_b = concat(xh, tpl) ----------
__global__ __launch_bounds__(256) void concat_dual(const float* __restrict__ tpl, const float* __restrict__ xh,
                                                   u16* __restrict__ ta, u16* __restrict__ tb) {
    int id = blockIdx.x * 256 + threadIdx.x;
    if (id >= N_ * HW_ * 16) return;
    int c8 = id & 15;
    int pix = id >> 4;
    int n = pix / HW_, p = pix % HW_;
    int c = c8 * 8;
    const float* s = (c < 64) ? tpl + ((size_t)n * 64 + c) * HW_ + p
                              : xh + ((size_t)n * 64 + (c - 64)) * HW_ + p;
    short8 vv;
#pragma unroll
    for (int j = 0; j < 8; ++j) vv[j] = f2b(s[(size_t)j * HW_]);
    *reinterpret_cast<short8*>(ta + (size_t)pix * 128 + c) = vv;
    *reinterpret_cast<short8*>(tb + (size_t)pix * 128 + ((c + 64) & 127)) = vv;
}

// ---------- core implicit-GEMM body, 32-px blocks (64 oc x 32 px, 4 waves m-stacked) ----------
// r in [0, 576): n = r/288, y = (r%288)/3, px0 = (r%3)*32
template <int IC, int OCST>
__device__ __forceinline__ void conv_core(const u16* __restrict__ X,
                                          const u16* __restrict__ A,
                                          const float* __restrict__ bias,
                                          float* __restrict__ out,
                                          int r, int mt, int t) {
    constexpr int K = IC * 9;
    constexpr int ICC = IC / 64;
    __shared__ __align__(16) u16 Xl[3][34][72];
    int n = r / 288;
    int rr = r % 288;
    int y = rr / 3, px0 = (rr % 3) * 32;
    int w = t >> 6, lane = t & 63, lm = lane & 15, q = lane >> 4;
    const u16* Arow = A + (size_t)(mt * 64 + w * 16 + lm) * K + q * 8;
    floatx4 acc[2];
#pragma unroll
    for (int a = 0; a < 2; ++a) acc[a] = {0.f, 0.f, 0.f, 0.f};
    const short8 zz = {0, 0, 0, 0, 0, 0, 0, 0};

    for (int icc = 0; icc < ICC; ++icc) {
        short8 af[9][2];
#pragma unroll
        for (int tap = 0; tap < 9; ++tap)
#pragma unroll
            for (int ks = 0; ks < 2; ++ks)
                af[tap][ks] = *reinterpret_cast<const short8*>(Arow + tap * IC + icc * 64 + ks * 32);
        __syncthreads();
        // stage 3 rows x 34 px x 64 ch: 816 short8 units
#pragma unroll
        for (int it = 0; it < 4; ++it) {
            int id = it * 256 + t;
            if (id < 816) {
                int ch8 = id & 7;
                int tmp = id >> 3;
                int pxl = tmp % 34, row = tmp / 34;
                int xg = px0 - 1 + pxl;
                int yg = y - 1 + row;
                bool vld = (yg >= 0) && (yg < 96) && (xg >= 0) && (xg < 96);
                short8 vv = zz;
                if (vld)
                    vv = *reinterpret_cast<const short8*>(
                        X + ((size_t)(n * HW_ + yg * 96 + xg)) * IC + icc * 64 + ch8 * 8);
                *reinterpret_cast<short8*>(&Xl[row][pxl][ch8 * 8]) = vv;
            }
        }
        __syncthreads();
#pragma unroll
        for (int tap = 0; tap < 9; ++tap) {
            int ky = tap / 3, kx = tap % 3;
#pragma unroll
            for (int ks = 0; ks < 2; ++ks) {
#pragma unroll
                for (int nf = 0; nf < 2; ++nf) {
                    short8 bv = *reinterpret_cast<const short8*>(&Xl[ky][nf * 16 + lm + kx][ks * 32 + q * 8]);
                    acc[nf] = __builtin_amdgcn_mfma_f32_16x16x32_bf16(af[tap][ks], bv, acc[nf], 0, 0, 0);
                }
            }
        }
    }
    int ocb = mt * 64 + w * 16 + q * 4;
#pragma unroll
    for (int nf = 0; nf < 2; ++nf) {
        int px = px0 + nf * 16 + lm;
#pragma unroll
        for (int rr2 = 0; rr2 < 4; ++rr2) {
            int oc = ocb + rr2;
            if (oc < OCST)
                out[((size_t)(n * OCST + oc)) * HW_ + y * 96 + px] = acc[nf][rr2] + bias[oc];
        }
    }
}

template <int IC, int OCST>
__global__ __launch_bounds__(256) void conv_gemm(const u16* __restrict__ X,
                                                 const u16* __restrict__ A,
                                                 const float* __restrict__ bias,
                                                 float* __restrict__ out) {
    conv_core<IC, OCST>(X, A, bias, out, blockIdx.x % 576, blockIdx.x / 576, threadIdx.x);
}

// quad-instance offset conv: grid 2304, inst = gx/576
__global__ __launch_bounds__(256) void conv_quad(const u16* __restrict__ X0, const u16* __restrict__ X1,
                                                 const u16* __restrict__ X2, const u16* __restrict__ X3,
                                                 const u16* __restrict__ A0, const u16* __restrict__ A1,
                                                 const u16* __restrict__ A2, const u16* __restrict__ A3,
                                                 const float* __restrict__ b0, const float* __restrict__ b1,
                                                 const float* __restrict__ b2, const float* __restrict__ b3,
                                                 float* __restrict__ o0, float* __restrict__ o1,
                                                 float* __restrict__ o2, float* __restrict__ o3) {
    int inst = blockIdx.x / 576, r = blockIdx.x % 576;
    const u16* X = (inst == 0) ? X0 : (inst == 1) ? X1 : (inst == 2) ? X2 : X3;
    const u16* A = (inst == 0) ? A0 : (inst == 1) ? A1 : (inst == 2) ? A2 : A3;
    const float* b = (inst == 0) ? b0 : (inst == 1) ? b1 : (inst == 2) ? b2 : b3;
    float* o = (inst == 0) ? o0 : (inst == 1) ? o1 : (inst == 2) ? o2 : o3;
    conv_core<C2_, 27>(X, A, b, o, r, 0, threadIdx.x);
}

// ---------- fused deformable conv core, 32-px blocks ----------
__device__ __forceinline__ void dcn_core(const u16* __restrict__ txh,
                                         const float* __restrict__ om,
                                         const u16* __restrict__ A,
                                         const float* __restrict__ bias,
                                         float* __restrict__ out,
                                         int r, int t) {
    __shared__ __align__(16) u16 Bl[32][72];
    __shared__ float s_wy[288], s_wx[288], s_m[288];
    __shared__ int s_y0[288], s_x0[288];
    int n = r / 288;
    int rr = r % 288;
    int y = rr / 3, px0 = (rr % 3) * 32;
    for (int e = t; e < 288; e += 256) {
        int k9 = e / 32, xl = e % 32;
        int x = px0 + xl;
        const float* ob = om + (size_t)n * 27 * HW_ + y * 96 + x;
        float dy = ob[(size_t)k9 * HW_];
        float dx = ob[(size_t)(9 + k9) * HW_];
        float ml = ob[(size_t)(18 + k9) * HW_];
        float py = (float)y + (float)(k9 / 3 - 1) + dy;
        float px = (float)x + (float)(k9 % 3 - 1) + dx;
        float fy = floorf(py), fx = floorf(px);
        s_y0[e] = (int)fy; s_x0[e] = (int)fx;
        s_wy[e] = py - fy; s_wx[e] = px - fx; s_m[e] = sigm(ml);
    }
    int w = t >> 6, lane = t & 63, lm = lane & 15, q = lane >> 4;
    const u16* Arow = A + (size_t)(w * 16 + lm) * 1152 + q * 8;
    floatx4 acc[2];
#pragma unroll
    for (int a = 0; a < 2; ++a) acc[a] = {0.f, 0.f, 0.f, 0.f};
    const u16* txn = txh + (size_t)n * HW_ * 128;
    const short8 zz = {0, 0, 0, 0, 0, 0, 0, 0};

    for (int kc = 0; kc < 18; ++kc) {
        int tap = kc >> 1, c0 = (kc & 1) * 64;
        short8 af[2];
#pragma unroll
        for (int ks = 0; ks < 2; ++ks)
            af[ks] = *reinterpret_cast<const short8*>(Arow + kc * 64 + ks * 32);
        __syncthreads();
        {   // staging: exactly one 8-ch unit per thread
            int px = t >> 3, ch8 = t & 7;
            int ce = tap * 32 + px;
            int y0 = s_y0[ce], x0 = s_x0[ce];
            float wy = s_wy[ce], wx = s_wx[ce], m = s_m[ce];
            float w00 = (1.f - wy) * (1.f - wx) * m;
            float w01 = (1.f - wy) * wx * m;
            float w10 = wy * (1.f - wx) * m;
            float w11 = wy * wx * m;
            bool yv0 = (y0 >= 0) & (y0 < 96), yv1 = (y0 >= -1) & (y0 < 95);
            bool xv0 = (x0 >= 0) & (x0 < 96), xv1 = (x0 >= -1) & (x0 < 95);
            const u16* base = txn + (long)(y0 * 96 + x0) * 128 + c0 + ch8 * 8;
            short8 v00 = (yv0 && xv0) ? *reinterpret_cast<const short8*>(base) : zz;
            short8 v01 = (yv0 && xv1) ? *reinterpret_cast<const short8*>(base + 128) : zz;
            short8 v10 = (yv1 && xv0) ? *reinterpret_cast<const short8*>(base + 96 * 128) : zz;
            short8 v11 = (yv1 && xv1) ? *reinterpret_cast<const short8*>(base + 96 * 128 + 128) : zz;
            short8 vv;
#pragma unroll
            for (int j = 0; j < 8; ++j) {
                float f = b2f(v00[j]) * w00 + b2f(v01[j]) * w01 +
                          b2f(v10[j]) * w10 + b2f(v11[j]) * w11;
                vv[j] = f2b(f);
            }
            *reinterpret_cast<short8*>(&Bl[px][ch8 * 8]) = vv;
        }
        __syncthreads();
#pragma unroll
        for (int ks = 0; ks < 2; ++ks)
#pragma unroll
            for (int nf = 0; nf < 2; ++nf) {
                short8 bv = *reinterpret_cast<const short8*>(&Bl[nf * 16 + lm][ks * 32 + q * 8]);
                acc[nf] = __builtin_amdgcn_mfma_f32_16x16x32_bf16(af[ks], bv, acc[nf], 0, 0, 0);
            }
    }
    int ocb = w * 16 + q * 4;
#pragma unroll
    for (int nf = 0; nf < 2; ++nf) {
        int px = px0 + nf * 16 + lm;
#pragma unroll
        for (int rr2 = 0; rr2 < 4; ++rr2) {
            int oc = ocb + rr2;
            out[((size_t)(n * CH_ + oc)) * HW_ + y * 96 + px] = acc[nf][rr2] + bias[oc];
        }
    }
}

// quad-instance dcn: grid 2304
__global__ __launch_bounds__(256) void dcn_quad(const u16* __restrict__ X0, const u16* __restrict__ X1,
                                                const u16* __restrict__ X2, const u16* __restrict__ X3,
                                                const float* __restrict__ om0, const float* __restrict__ om1,
                                                const float* __restrict__ om2, const float* __restrict__ om3,
                                                const u16* __restrict__ A0, const u16* __restrict__ A1,
                                                const u16* __restrict__ A2, const u16* __restrict__ A3,
                                                const float* __restrict__ b0, const float* __restrict__ b1,
                                                const float* __restrict__ b2, const float* __restrict__ b3,
                                                float* __restrict__ o0, float* __restrict__ o1,
                                                float* __restrict__ o2, float* __restrict__ o3) {
    int inst = blockIdx.x / 576, r = blockIdx.x % 576;
    const u16* X = (inst == 0) ? X0 : (inst == 1) ? X1 : (inst == 2) ? X2 : X3;
    const float* om = (inst == 0) ? om0 : (inst == 1) ? om1 : (inst == 2) ? om2 : om3;
    const u16* A = (inst == 0) ? A0 : (inst == 1) ? A1 : (inst == 2) ? A2 : A3;
    const float* b = (inst == 0) ? b0 : (inst == 1) ? b1 : (inst == 2) ? b2 : b3;
    float* o = (inst == 0) ? o0 : (inst == 1) ? o1 : (inst == 2) ? o2 : o3;
    dcn_core(X, om, A, b, o, r, threadIdx.x);
}

// ---------- fused NCF v4: LDS-staged window (16-px strip) ----------
__global__ __launch_bounds__(256, 4) void ncf2(const u16* __restrict__ in0, const u16* __restrict__ in1,
                                               u16* __restrict__ out0, u16* __restrict__ out1) {
    __shared__ __align__(16) u16 sF2[7][28][72];
    __shared__ __align__(16) u16 sF1[16][72];
    __shared__ float sc[16][52];
    int t = threadIdx.x;
    int inst = blockIdx.x / 1152, bb = blockIdx.x % 1152;
    const u16* txh = inst ? in1 : in0;
    u16* txh2 = inst ? out1 : out0;
    int n = bb / 576, rem = bb % 576;
    int y = rem / 6, x0 = (rem % 6) * 16;
    const u16* base = txh + (size_t)n * HW_ * 128;
    const short8 zz = {0, 0, 0, 0, 0, 0, 0, 0};

    for (int id = t; id < 1568; id += 256) {
        int ch8 = id & 7;
        int tmp = id >> 3;
        int px = tmp % 28, row = tmp / 28;
        int yy = y + row * 2 - 6;
        int xg = x0 - 6 + px;
        short8 vv = zz;
        if (yy >= 0 && yy < 96 && xg >= 0 && xg < 96)
            vv = *reinterpret_cast<const short8*>(base + (size_t)(yy * 96 + xg) * 128 + ch8 * 8);
        *reinterpret_cast<short8*>(&sF2[row][px][ch8 * 8]) = vv;
    }
    if (t < 128) {
        int ch8 = t & 7, lp0 = t >> 3;
        short8 vv = *reinterpret_cast<const short8*>(base + (size_t)(y * 96 + x0 + lp0) * 128 + 64 + ch8 * 8);
        *reinterpret_cast<short8*>(&sF1[lp0][ch8 * 8]) = vv;
    }
    __syncthreads();

    int lp = t >> 4, j = t & 15;
    for (int k = j; k < 49; k += 16) {
        int ky = k / 7, kx = k % 7;
        const u16* f2p = &sF2[ky][lp + 2 * kx][0];
        const u16* f1p = &sF1[lp][0];
        float s = 0.f;
#pragma unroll
        for (int c8 = 0; c8 < 8; ++c8) {
            short8 a = *reinterpret_cast<const short8*>(f1p + c8 * 8);
            short8 b = *reinterpret_cast<const short8*>(f2p + c8 * 8);
#pragma unroll
            for (int u = 0; u < 8; ++u) s += b2f(a[u]) * b2f(b[u]);
        }
        sc[lp][k] = s * 0.125f;
    }
    float mx = -1e30f;
    for (int k = j; k < 49; k += 16) mx = fmaxf(mx, sc[lp][k]);
#pragma unroll
    for (int m = 1; m <= 8; m <<= 1) mx = fmaxf(mx, __shfl_xor(mx, m, 64));
    float e[4];
    float sum = 0.f;
    int cnt = 0;
    for (int k = j; k < 49; k += 16) { e[cnt] = __expf(sc[lp][k] - mx); sum += e[cnt]; ++cnt; }
#pragma unroll
    for (int m = 1; m <= 8; m <<= 1) sum += __shfl_xor(sum, m, 64);
    float inv = 1.f / sum;
    cnt = 0;
    for (int k = j; k < 49; k += 16) sc[lp][k] = e[cnt++] * inv;
    __syncthreads();
    int ch0 = j * 4;
    float acc[4];
#pragma unroll
    for (int u = 0; u < 4; ++u) acc[u] = 0.f;
#pragma unroll
    for (int k = 0; k < 49; ++k) {
        int ky = k / 7, kx = k % 7;
        float a = sc[lp][k];
        bh4 f2 = *reinterpret_cast<const bh4*>(&sF2[ky][lp + 2 * kx][ch0]);
#pragma unroll
        for (int u = 0; u < 4; ++u) acc[u] += a * b2f(f2[u]);
    }
    int p = y * 96 + x0 + lp;
    u16* obase = txh2 + (size_t)n * HW_ * 128 + (size_t)p * 128;
    bh4 ro;
#pragma unroll
    for (int u = 0; u < 4; ++u) ro[u] = f2b(acc[u]);
    *reinterpret_cast<bh4*>(obase + ch0) = ro;
    *reinterpret_cast<bh4*>(obase + 64 + ch0) =
        *reinterpret_cast<const bh4*>(&sF1[lp][ch0]);
}

// ---------- dual GRU gate: inst a -> NHWC bf16, inst b -> NCHW f32 ----------
__global__ __launch_bounds__(256) void gate_dual(const float* __restrict__ dz_a, const float* __restrict__ dh_a,
                                                 const float* __restrict__ t_a, u16* __restrict__ dst_a,
                                                 const float* __restrict__ dz_b, const float* __restrict__ dh_b,
                                                 const float* __restrict__ t_b, float* __restrict__ dst_b) {
    int inst = blockIdx.x / 576, bb = blockIdx.x % 576;
    int id = bb * 256 + threadIdx.x;
    int c8 = id & 7;
    int pix = id >> 3;
    int n = pix / HW_, p = pix % HW_;
    const float* zpre = inst ? dz_b : dz_a;
    const float* hpre = inst ? dh_b : dh_a;
    const float* tt = inst ? t_b : t_a;
    if (!inst) {
        short8 vv;
#pragma unroll
        for (int j = 0; j < 8; ++j) {
            size_t idx = ((size_t)n * CH_ + c8 * 8 + j) * HW_ + p;
            float z = sigm(zpre[idx]);
            float xt = tanhf(hpre[idx]);
            vv[j] = f2b((1.f - z) * tt[idx] + z * xt);
        }
        *reinterpret_cast<short8*>(dst_a + (size_t)pix * CH_ + c8 * 8) = vv;
    } else {
#pragma unroll
        for (int j = 0; j < 8; ++j) {
            size_t idx = ((size_t)n * CH_ + c8 * 8 + j) * HW_ + p;
            float z = sigm(zpre[idx]);
            float xt = tanhf(hpre[idx]);
            dst_b[idx] = (1.f - z) * tt[idx] + z * xt;
        }
    }
}

extern "C" void kernel_launch(void* const* d_in, const int* in_sizes, int n_in,
                              void* d_out, int out_size, void* d_ws, size_t ws_size,
                              hipStream_t stream) {
    const float* x     = (const float*)d_in[0];
    const float* tpl   = (const float*)d_in[1];
    const float* w_in  = (const float*)d_in[2];
    const float* b_in  = (const float*)d_in[3];
    const float* w_out = (const float*)d_in[4];
    const float* b_out = (const float*)d_in[5];
    const float *pw[4], *pb[4], *pow_[4], *pob[4];
    for (int i = 0; i < 4; ++i) {           // 0=enh_z 1=enh_h 2=upd_z 3=upd_h
        pw[i]   = (const float*)d_in[6 + 4 * i];
        pb[i]   = (const float*)d_in[7 + 4 * i];
        pow_[i] = (const float*)d_in[8 + 4 * i];
        pob[i]  = (const float*)d_in[9 + 4 * i];
    }
    float* out_main = (float*)d_out;
    float* out_ntpl = out_main + (size_t)N_ * CIN_ * HW_;

    // ---- workspace (~60 MB; no aliasing) ----
    u16* Aws = (u16*)d_ws;
    u16* xT     = Aws + A_TOT;                        // (N,96,96,256) bf16
    u16* txh_a  = xT + (size_t)N_ * HW_ * CIN_;       // (N,96,96,128) bf16
    u16* txh_b  = txh_a + (size_t)N_ * HW_ * C2_;
    u16* txh2_a = txh_b + (size_t)N_ * HW_ * C2_;
    u16* txh2_b = txh2_a + (size_t)N_ * HW_ * C2_;
    u16* xeh    = txh2_b + (size_t)N_ * HW_ * C2_;    // (N,96,96,64) bf16
    float* fws = (float*)(xeh + (size_t)N_ * HW_ * CH_);
    size_t off = 0;
    float* xh   = fws + off; off += (size_t)N_ * CH_ * HW_;
    float* om0  = fws + off; off += (size_t)N_ * 27 * HW_;
    float* om1  = fws + off; off += (size_t)N_ * 27 * HW_;
    float* om2  = fws + off; off += (size_t)N_ * 27 * HW_;
    float* om3  = fws + off; off += (size_t)N_ * 27 * HW_;
    float* dz_a = fws + off; off += (size_t)N_ * CH_ * HW_;
    float* dz_b = fws + off; off += (size_t)N_ * CH_ * HW_;
    float* dh_a = fws + off; off += (size_t)N_ * CH_ * HW_;
    float* dh_b = fws + off; off += (size_t)N_ * CH_ * HW_;

    cvt_weights<<<(A_TOT + 255) / 256, 256, 0, stream>>>(
        w_in, w_out, pow_[0], pow_[1], pow_[2], pow_[3], pw[0], pw[1], pw[2], pw[3], Aws);
    to_nhwc<<<2304, 256, 0, stream>>>(x, xT, CIN_);
    conv_gemm<CIN_, 64><<<576, 256, 0, stream>>>(xT, Aws + A_IN_OFF, b_in, xh);

    // instance a = enh (x32=tpl, tt=xh), instance b = upd (x32=xh, tt=tpl)
    concat_dual<<<1152, 256, 0, stream>>>(tpl, xh, txh_a, txh_b);
    ncf2<<<2304, 256, 0, stream>>>(txh_a, txh_b, txh2_a, txh2_b);
    // quad instances: 0=(a,z) 1=(b,z) 2=(a,h) 3=(b,h)
    conv_quad<<<2304, 256, 0, stream>>>(
        txh_a, txh_b, txh2_a, txh2_b,
        Aws + A_OFF_OFF + 0 * A_OFF_SZ, Aws + A_OFF_OFF + 2 * A_OFF_SZ,
        Aws + A_OFF_OFF + 1 * A_OFF_SZ, Aws + A_OFF_OFF + 3 * A_OFF_SZ,
        pob[0], pob[2], pob[1], pob[3], om0, om1, om2, om3);
    dcn_quad<<<2304, 256, 0, stream>>>(
        txh_a, txh_b, txh2_a, txh2_b, om0, om1, om2, om3,
        Aws + A_DCN_OFF + 0 * A_DCN_SZ, Aws + A_DCN_OFF + 2 * A_DCN_SZ,
        Aws + A_DCN_OFF + 1 * A_DCN_SZ, Aws + A_DCN_OFF + 3 * A_DCN_SZ,
        pb[0], pb[2], pb[1], pb[3], dz_a, dz_b, dh_a, dh_b);
    gate_dual<<<1152, 256, 0, stream>>>(dz_a, dh_a, xh, xeh, dz_b, dh_b, tpl, out_ntpl);

    conv_gemm<CH_, 256><<<2304, 256, 0, stream>>>(xeh, Aws + A_OUT_OFF, b_out, out_main);
}